// Round 6
// baseline (399.770 us; speedup 1.0000x reference)
//
#include <hip/hip_runtime.h>
#include <math.h>

// FactorizationMachine: out = sigmoid( X@fc_w + fc_b + 0.5*( sum_d (X@w)_d^2 - (X^2)@g ) ),
// g[f] = sum_d w[f,d]^2 computed inline from the w slice each wave already loads.
//
// R5 redesign (concurrency-starved diagnosis): prior rounds ran at 1 wave/SIMD
// (136 fp32 accumulators + staging regs > 256 in the unified VGPR file) and were
// limited by outstanding-bytes (Little's law), not bytes moved.
//  - X staged to LDS via __builtin_amdgcn_global_load_lds (DMA; no VGPR cost),
//    8 KB tiles (8 rows x 64 float4), TRIPLE-buffered, 2 tiles in flight,
//    raw s_barrier + counted s_waitcnt vmcnt(4/2/0)  (T3/T4; __syncthreads would
//    drain vmcnt(0) and serialize the pipeline).
//  - D-split: wave w owns factor columns [4w,4w+4) (wave 3 also owns the linear
//    term). Accumulators 48/thread -> ~105 VGPRs. Each X byte is read by 4 waves
//    from LDS (the reason LDS staging pays), W is read once per block per tile
//    (16 KB) and is L3-resident (3.2 MB) -> HBM = X once = 819 MB.

constexpr int B_ROWS  = 4096;
constexpr int F_FEAT  = 50000;
constexpr int NF4     = F_FEAT / 4;              // 12500 float4 groups per row
constexpr int ROWS    = 8;                       // rows per block
constexpr int THREADS = 256;
constexpr int TILE    = 64;                      // f4 groups per tile (1 KB/row)
constexpr int NTILES  = (NF4 + TILE - 1) / TILE; // 196 (last tile: 20 valid)

typedef float f32x4 __attribute__((ext_vector_type(4)));

__device__ __forceinline__ void gload16(const f32x4* gsrc, f32x4* ldst) {
    __builtin_amdgcn_global_load_lds(
        (const __attribute__((address_space(1))) void*)gsrc,
        (__attribute__((address_space(3))) void*)ldst, 16, 0, 0);
}

__global__ __launch_bounds__(THREADS, 2)
void fm_kernel(const float* __restrict__ X,
               const float* __restrict__ fcw,
               const float* __restrict__ fcb,
               const float* __restrict__ W,
               float* __restrict__ out)
{
    __shared__ __align__(16) float xbuf[3][ROWS][TILE * 4];  // 24 KB
    __shared__ float epi_s[4][ROWS][4];
    __shared__ float epi_sq[4][ROWS];
    __shared__ float epi_lin[ROWS];

    const int tid  = threadIdx.x;
    const int lane = tid & 63;
    const int wid  = tid >> 6;                   // wave id = factor-column block
    const int row0 = blockIdx.x * ROWS;

    const f32x4* X4  = reinterpret_cast<const f32x4*>(X);
    const f32x4* W4  = reinterpret_cast<const f32x4*>(W);
    const f32x4* FW4 = reinterpret_cast<const f32x4*>(fcw);

    float s[ROWS][4];
    float sq[ROWS];
    float lin[ROWS];
#pragma unroll
    for (int r = 0; r < ROWS; ++r) {
        sq[r] = 0.f; lin[r] = 0.f;
#pragma unroll
        for (int k = 0; k < 4; ++k) s[r][k] = 0.f;
    }

    // Wave w DMA-stages rows {2w, 2w+1}: LDS dst = uniform base + lane*16 (linear),
    // global src per-lane (f4 = tile*64 + lane, clamped in the last tile).
    auto stage = [&](int t, int b) {
        int f4 = t * TILE + lane;
        if (f4 >= NF4) f4 = NF4 - 1;             // clamp: garbage staged, compute skips
#pragma unroll
        for (int rr = 0; rr < 2; ++rr) {
            const int r = wid * 2 + rr;
            gload16(X4 + (size_t)(row0 + r) * NF4 + f4,
                    reinterpret_cast<f32x4*>(&xbuf[b][r][0]));
        }
    };

    stage(0, 0);
    stage(1, 1);

    for (int t = 0; t < NTILES; ++t) {
        const int b = t % 3;
        if (t + 2 < NTILES) {
            stage(t + 2, (t + 2) % 3);
            asm volatile("s_waitcnt vmcnt(4)" ::: "memory");  // tile t landed; t+1,t+2 in flight
        } else if (t + 1 < NTILES) {
            asm volatile("s_waitcnt vmcnt(2)" ::: "memory");
        } else {
            asm volatile("s_waitcnt vmcnt(0)" ::: "memory");
        }
        __builtin_amdgcn_s_barrier();
        asm volatile("" ::: "memory");

        // ---- compute tile t from xbuf[b] ----
        f32x4 xq[ROWS];                           // lane's 4 features x 8 rows
#pragma unroll
        for (int r = 0; r < ROWS; ++r)
            xq[r] = reinterpret_cast<const f32x4*>(&xbuf[b][r][0])[lane];

        const int f4g = t * TILE + lane;
        if (f4g < NF4) {
            const size_t wbase = (size_t)f4g * 16 + wid;  // f32x4 idx: (f4g*4+j)*4 + wid
            f32x4 fw;
            if (wid == 3) fw = FW4[f4g];
#pragma unroll
            for (int j = 0; j < 4; ++j) {
                const f32x4 wv = W4[wbase + j * 4];       // this wave's 4 w-columns
                float gpn = wv[0] * wv[0];
                gpn = fmaf(wv[1], wv[1], gpn);
                gpn = fmaf(wv[2], wv[2], gpn);
                gpn = fmaf(wv[3], wv[3], gpn);
                gpn *= -0.5f;
#pragma unroll
                for (int r = 0; r < ROWS; ++r) {
                    const float x  = xq[r][j];
                    const float x2 = x * x;
                    sq[r]  = fmaf(x2, gpn, sq[r]);
                    s[r][0] = fmaf(x, wv[0], s[r][0]);
                    s[r][1] = fmaf(x, wv[1], s[r][1]);
                    s[r][2] = fmaf(x, wv[2], s[r][2]);
                    s[r][3] = fmaf(x, wv[3], s[r][3]);
                    if (wid == 3) lin[r] = fmaf(x, fw[j], lin[r]);
                }
            }
        }

        asm volatile("" ::: "memory");
        __builtin_amdgcn_s_barrier();             // buf[b] free for reuse next iter
    }

    // ---- epilogue: per-wave 64-lane butterfly, combine across waves via LDS ----
#pragma unroll
    for (int r = 0; r < ROWS; ++r) {
#pragma unroll
        for (int k = 0; k < 4; ++k) {
            float v = s[r][k];
#pragma unroll
            for (int m = 32; m >= 1; m >>= 1) v += __shfl_xor(v, m, 64);
            if (lane == 0) epi_s[wid][r][k] = v;
        }
        float v = sq[r];
#pragma unroll
        for (int m = 32; m >= 1; m >>= 1) v += __shfl_xor(v, m, 64);
        if (lane == 0) epi_sq[wid][r] = v;
    }
    if (wid == 3) {
#pragma unroll
        for (int r = 0; r < ROWS; ++r) {
            float v = lin[r];
#pragma unroll
            for (int m = 32; m >= 1; m >>= 1) v += __shfl_xor(v, m, 64);
            if (lane == 0) epi_lin[r] = v;
        }
    }
    __syncthreads();

    if (tid < ROWS) {
        const int r = tid;
        float ss = 0.f;
#pragma unroll
        for (int w = 0; w < 4; ++w)
#pragma unroll
            for (int k = 0; k < 4; ++k) {
                const float v = epi_s[w][r][k];
                ss = fmaf(v, v, ss);
            }
        const float sqs = epi_sq[0][r] + epi_sq[1][r] + epi_sq[2][r] + epi_sq[3][r];
        const float logit = epi_lin[r] + fcb[0] + sqs + 0.5f * ss;
        out[row0 + r] = 1.0f / (1.0f + expf(-logit));
    }
}

extern "C" void kernel_launch(void* const* d_in, const int* in_sizes, int n_in,
                              void* d_out, int out_size, void* d_ws, size_t ws_size,
                              hipStream_t stream)
{
    const float* X   = (const float*)d_in[0];
    const float* fcw = (const float*)d_in[1];
    const float* fcb = (const float*)d_in[2];
    const float* W   = (const float*)d_in[3];
    float* out = (float*)d_out;

    dim3 grid(B_ROWS / ROWS);   // 512 blocks, 2 per CU
    dim3 block(THREADS);
    hipLaunchKernelGGL(fm_kernel, grid, block, 0, stream, X, fcw, fcb, W, out);
}